// Round 8
// baseline (689.776 us; speedup 1.0000x reference)
//
#include <hip/hip_runtime.h>
#include <hip/hip_bf16.h>

#define D 64

typedef unsigned short u16;
typedef __attribute__((ext_vector_type(8))) unsigned short u16x8;

static __device__ __forceinline__ u16 f2bf(float f) {
    unsigned u = __float_as_uint(f);
    unsigned r = (u + 0x7FFFu + ((u >> 16) & 1u)) >> 16;   // RNE
    return (u16)r;
}
static __device__ __forceinline__ float bf2f(u16 h) {
    return __uint_as_float(((unsigned)h) << 16);
}

// ---------------------------------------------------------------------------
__global__ void out_init_kernel(float* __restrict__ out, const float* __restrict__ bout, int G) {
    int i = blockIdx.x * blockDim.x + threadIdx.x;
    if (i < G) out[i] = bout[0];
}

// ---------------------------------------------------------------------------
// CSR build: histogram -> scan
// ---------------------------------------------------------------------------
__global__ void deg_hist_kernel(const int* __restrict__ ei, int* __restrict__ deg, int E) {
    int e = blockIdx.x * blockDim.x + threadIdx.x;
    if (e < E) atomicAdd(&deg[ei[E + e]], 1);
}

__global__ __launch_bounds__(1024) void scan1_kernel(
    const int* __restrict__ deg, int* __restrict__ off, int* __restrict__ bsum, int N)
{
    __shared__ int sh[1024];
    int t = threadIdx.x;
    int i = blockIdx.x * 1024 + t;
    int v = (i < N) ? deg[i] : 0;
    sh[t] = v;
    __syncthreads();
#pragma unroll
    for (int o = 1; o < 1024; o <<= 1) {
        int u = (t >= o) ? sh[t - o] : 0;
        __syncthreads();
        sh[t] += u;
        __syncthreads();
    }
    if (i < N) off[i] = sh[t] - v;
    if (t == 1023) bsum[blockIdx.x] = sh[t];
}

__global__ __launch_bounds__(128) void scan2_kernel(
    const int* __restrict__ bsum, int* __restrict__ boff, int nb)
{
    __shared__ int sh[128];
    int t = threadIdx.x;
    int v = (t < nb) ? bsum[t] : 0;
    sh[t] = v;
    __syncthreads();
#pragma unroll
    for (int o = 1; o < 128; o <<= 1) {
        int u = (t >= o) ? sh[t - o] : 0;
        __syncthreads();
        sh[t] += u;
        __syncthreads();
    }
    if (t < nb) boff[t] = sh[t] - v;
}

__global__ void scan3_kernel(int* __restrict__ off, const int* __restrict__ boff, int N) {
    int i = blockIdx.x * blockDim.x + threadIdx.x;
    if (i < N) off[i] += boff[i >> 10];
}

// ---------------------------------------------------------------------------
// build: fused scatter + reorder.  Wave handles 4 edges, 16 lanes/edge.
// Sequential fp32 ea read, bf16 row (128B) write to CSR slot.
// ---------------------------------------------------------------------------
__global__ __launch_bounds__(256) void build_kernel(
    const float* __restrict__ ea, const int* __restrict__ ei,
    const int* __restrict__ off, int* __restrict__ cur,
    int* __restrict__ src_csr, u16* __restrict__ ea_csr, int E)
{
    const int lane = threadIdx.x & 63;
    const int q = lane & 15, g = lane >> 4;
    const long long wv = (long long)blockIdx.x * 4 + (threadIdx.x >> 6);
    const int e = (int)(wv * 4) + g;

    int p = 0, s = 0;
    if (e < E && q == 0) {
        int d = ei[E + e];
        s = ei[e];
        p = off[d] + atomicAdd(&cur[d], 1);
    }
    p = __shfl(p, lane & 48, 64);        // broadcast group leader's slot
    if (e >= E) return;

    float4 v = *(const float4*)&ea[(size_t)e * D + q * 4];
    ushort4 o;
    o.x = f2bf(v.x); o.y = f2bf(v.y); o.z = f2bf(v.z); o.w = f2bf(v.w);
    *(ushort4*)&ea_csr[(size_t)p * D + q * 4] = o;
    if (q == 0) src_csr[p] = s;
}

// ---------------------------------------------------------------------------
// convx: fp32 node features -> bf16 (identity order, fully sequential)
// ---------------------------------------------------------------------------
__global__ __launch_bounds__(256) void convx_kernel(
    const float* __restrict__ xf, u16* __restrict__ xb, long long n4)
{
    long long i = (long long)blockIdx.x * blockDim.x + threadIdx.x;
    if (i >= n4) return;
    float4 v = ((const float4*)xf)[i];
    ushort4 o;
    o.x = f2bf(v.x); o.y = f2bf(v.y); o.z = f2bf(v.z); o.w = f2bf(v.w);
    ((ushort4*)xb)[i] = o;
}

// ---------------------------------------------------------------------------
// fused layer: per node — gather-aggregate (8 lanes/edge, 8 edges in flight)
// -> shfl reduce -> h into wave-local LDS -> register-pinned-weight MLP.
// The MLP's VALU work overlaps the next node's / other waves' gathers.
// LAST=1 fuses global_add_pool + Wout.
// ---------------------------------------------------------------------------
template <int LAST>
__global__ __launch_bounds__(256, 2) void layer_kernel(
    const u16* __restrict__ xbf, u16* __restrict__ xout,
    const u16* __restrict__ ea_csr, const int* __restrict__ src_csr,
    const int* __restrict__ off, const int* __restrict__ deg,
    const float* __restrict__ W1, const float* __restrict__ b1,
    const float* __restrict__ W2, const float* __restrict__ b2,
    const int* __restrict__ batch, const float* __restrict__ Wout,
    float* __restrict__ out, int N, int chunk)
{
    __shared__ __align__(16) float sh[4][D];
    __shared__ __align__(16) float sh2[4][D];

    const int lane = threadIdx.x & 63;
    const int wid  = threadIdx.x >> 6;
    const int sub  = lane & 7;        // dim octet: dims [sub*8, sub*8+8)
    const int g    = lane >> 3;       // edge slot 0..7

    float w1[D], w2[D];
#pragma unroll
    for (int k = 0; k < D; ++k) w1[k] = W1[k * D + lane];
#pragma unroll
    for (int k = 0; k < D; ++k) w2[k] = W2[k * D + lane];
#pragma unroll
    for (int k = 0; k < D; ++k) { asm volatile("" : "+v"(w1[k])); asm volatile("" : "+v"(w2[k])); }
    const float b1l = b1[lane];
    const float b2l = b2[lane];
    const float wo  = LAST ? Wout[lane] : 0.f;

    const int wv = (blockIdx.x << 2) + wid;
    int n0 = wv * chunk;
    if (n0 >= N) return;
    int n1 = min(n0 + chunk, N);

    float gsum = 0.f;
    int   curg = -1;

    for (int n = n0; n < n1; ++n) {
        // ---- gather-aggregate ----
        const int p0 = off[n];
        const int dg = deg[n];

        float a0=0.f,a1=0.f,a2=0.f,a3=0.f,a4=0.f,a5=0.f,a6=0.f,a7=0.f;
        int base = 0;
        for (; base + 8 <= dg; base += 8) {
            int s = src_csr[p0 + base + g];
            u16x8 ev = *(const u16x8*)&ea_csr[(size_t)(p0 + base + g) * D + sub * 8];
            u16x8 xv = *(const u16x8*)&xbf[(size_t)s * D + sub * 8];
            a0 += fmaxf(bf2f(xv[0]) + bf2f(ev[0]), 0.f);
            a1 += fmaxf(bf2f(xv[1]) + bf2f(ev[1]), 0.f);
            a2 += fmaxf(bf2f(xv[2]) + bf2f(ev[2]), 0.f);
            a3 += fmaxf(bf2f(xv[3]) + bf2f(ev[3]), 0.f);
            a4 += fmaxf(bf2f(xv[4]) + bf2f(ev[4]), 0.f);
            a5 += fmaxf(bf2f(xv[5]) + bf2f(ev[5]), 0.f);
            a6 += fmaxf(bf2f(xv[6]) + bf2f(ev[6]), 0.f);
            a7 += fmaxf(bf2f(xv[7]) + bf2f(ev[7]), 0.f);
        }
        const int rem = dg - base;
        if (g < rem) {
            int s = src_csr[p0 + base + g];
            u16x8 ev = *(const u16x8*)&ea_csr[(size_t)(p0 + base + g) * D + sub * 8];
            u16x8 xv = *(const u16x8*)&xbf[(size_t)s * D + sub * 8];
            a0 += fmaxf(bf2f(xv[0]) + bf2f(ev[0]), 0.f);
            a1 += fmaxf(bf2f(xv[1]) + bf2f(ev[1]), 0.f);
            a2 += fmaxf(bf2f(xv[2]) + bf2f(ev[2]), 0.f);
            a3 += fmaxf(bf2f(xv[3]) + bf2f(ev[3]), 0.f);
            a4 += fmaxf(bf2f(xv[4]) + bf2f(ev[4]), 0.f);
            a5 += fmaxf(bf2f(xv[5]) + bf2f(ev[5]), 0.f);
            a6 += fmaxf(bf2f(xv[6]) + bf2f(ev[6]), 0.f);
            a7 += fmaxf(bf2f(xv[7]) + bf2f(ev[7]), 0.f);
        }

#pragma unroll
        for (int o = 8; o < 64; o <<= 1) {
            a0 += __shfl_xor(a0, o, 64);  a1 += __shfl_xor(a1, o, 64);
            a2 += __shfl_xor(a2, o, 64);  a3 += __shfl_xor(a3, o, 64);
            a4 += __shfl_xor(a4, o, 64);  a5 += __shfl_xor(a5, o, 64);
            a6 += __shfl_xor(a6, o, 64);  a7 += __shfl_xor(a7, o, 64);
        }

        if (g == 0) {                      // deposit h into wave-local LDS
            u16x8 xs = *(const u16x8*)&xbf[(size_t)n * D + sub * 8];
            float4 lo, hi;
            lo.x = a0 + bf2f(xs[0]); lo.y = a1 + bf2f(xs[1]);
            lo.z = a2 + bf2f(xs[2]); lo.w = a3 + bf2f(xs[3]);
            hi.x = a4 + bf2f(xs[4]); hi.y = a5 + bf2f(xs[5]);
            hi.z = a6 + bf2f(xs[6]); hi.w = a7 + bf2f(xs[7]);
            *(float4*)&sh[wid][sub * 8]     = lo;
            *(float4*)&sh[wid][sub * 8 + 4] = hi;
        }

        // ---- MLP (wave-synchronous LDS broadcast, pinned weights) ----
        float t0 = 0.f, t1 = 0.f, t2 = 0.f, t3 = 0.f;
#pragma unroll
        for (int k = 0; k < D; k += 4) {
            float4 hk = *(const float4*)&sh[wid][k];
            t0 = fmaf(hk.x, w1[k + 0], t0);
            t1 = fmaf(hk.y, w1[k + 1], t1);
            t2 = fmaf(hk.z, w1[k + 2], t2);
            t3 = fmaf(hk.w, w1[k + 3], t3);
        }
        float hid = fmaxf(((t0 + t1) + (t2 + t3)) + b1l, 0.f);
        sh2[wid][lane] = hid;

        float s0 = 0.f, s1 = 0.f, s2 = 0.f, s3 = 0.f;
#pragma unroll
        for (int k = 0; k < D; k += 4) {
            float4 hk = *(const float4*)&sh2[wid][k];
            s0 = fmaf(hk.x, w2[k + 0], s0);
            s1 = fmaf(hk.y, w2[k + 1], s1);
            s2 = fmaf(hk.z, w2[k + 2], s2);
            s3 = fmaf(hk.w, w2[k + 3], s3);
        }
        float r = fmaxf(((s0 + s1) + (s2 + s3)) + b2l, 0.f);

        if (LAST) {
            float s = r * wo;
#pragma unroll
            for (int o = 32; o; o >>= 1) s += __shfl_xor(s, o, 64);
            int gb = batch[n];
            if (gb != curg) {
                if (curg >= 0 && lane == 0) atomicAdd(&out[curg], gsum);
                curg = gb;
                gsum = s;
            } else {
                gsum += s;
            }
        } else {
            xout[(size_t)n * D + lane] = f2bf(r);
        }
    }
    if (LAST && curg >= 0 && lane == 0) atomicAdd(&out[curg], gsum);
}

// ---------------------------------------------------------------------------
extern "C" void kernel_launch(void* const* d_in, const int* in_sizes, int n_in,
                              void* d_out, int out_size, void* d_ws, size_t ws_size,
                              hipStream_t stream) {
    const float* x     = (const float*)d_in[0];
    const int*   ei    = (const int*)d_in[1];
    const float* ea    = (const float*)d_in[2];
    const int*   batch = (const int*)d_in[3];
    const float* W1    = (const float*)d_in[4];
    const float* b1    = (const float*)d_in[5];
    const float* W2    = (const float*)d_in[6];
    const float* b2    = (const float*)d_in[7];
    const float* Wout  = (const float*)d_in[8];
    const float* bout  = (const float*)d_in[9];
    float* out = (float*)d_out;

    const int N = in_sizes[0] / D;   // 100000
    const int E = in_sizes[1] / 2;   // 1200000
    const int G = out_size;          // 128

    // ---- workspace layout ----
    char* w = (char*)d_ws;
    u16*   xbfA    = (u16*)w;              w += (size_t)N * D * sizeof(u16);
    u16*   xbfB    = (u16*)w;              w += (size_t)N * D * sizeof(u16);
    int*   src_csr = (int*)w;              w += (size_t)E * sizeof(int);
    int*   deg     = (int*)w;              w += (size_t)N * sizeof(int);
    int*   off     = (int*)w;              w += (size_t)N * sizeof(int);
    int*   cur     = (int*)w;              w += (size_t)N * sizeof(int);
    int*   bsum    = (int*)w;              w += 128 * sizeof(int);
    int*   boff    = (int*)w;              w += 128 * sizeof(int);
    u16*   ea_csr  = (u16*)w;              // E*D*2 bytes

    const int nScanBlocks = (N + 1023) / 1024;
    const int edgeBlocks  = (E + 255) / 256;
    const int buildBlocks = (E + 15) / 16;

    const long long nx4 = (long long)N * D / 4;
    const int convxBlocks = (int)((nx4 + 255) / 256);

    const int layerWaves  = 8192;
    const int layerBlocks = layerWaves / 4;
    const int chunk       = (N + layerWaves - 1) / layerWaves;   // 13

    out_init_kernel<<<(G + 127) / 128, 128, 0, stream>>>(out, bout, G);

    // ---- CSR build + bf16 edge reorder + x0 bf16 convert ----
    hipMemsetAsync(deg, 0, (size_t)N * sizeof(int), stream);
    hipMemsetAsync(cur, 0, (size_t)N * sizeof(int), stream);
    deg_hist_kernel<<<edgeBlocks, 256, 0, stream>>>(ei, deg, E);
    scan1_kernel<<<nScanBlocks, 1024, 0, stream>>>(deg, off, bsum, N);
    scan2_kernel<<<1, 128, 0, stream>>>(bsum, boff, nScanBlocks);
    scan3_kernel<<<(N + 255) / 256, 256, 0, stream>>>(off, boff, N);
    build_kernel<<<buildBlocks, 256, 0, stream>>>(ea, ei, off, cur, src_csr, ea_csr, E);
    convx_kernel<<<convxBlocks, 256, 0, stream>>>(x, xbfA, nx4);

    // ---- 3 fused layers ----
    u16* xcur = xbfA;
    u16* xnxt = xbfB;
    for (int l = 0; l < 3; ++l) {
        if (l < 2) {
            layer_kernel<0><<<layerBlocks, 256, 0, stream>>>(xcur, xnxt,
                ea_csr, src_csr, off, deg,
                W1 + l * D * D, b1 + l * D, W2 + l * D * D, b2 + l * D,
                batch, Wout, out, N, chunk);
            u16* t = xcur; xcur = xnxt; xnxt = t;
        } else {
            layer_kernel<1><<<layerBlocks, 256, 0, stream>>>(xcur, nullptr,
                ea_csr, src_csr, off, deg,
                W1 + l * D * D, b1 + l * D, W2 + l * D * D, b2 + l * D,
                batch, Wout, out, N, chunk);
        }
    }
}

// Round 9
// 544.825 us; speedup vs baseline: 1.2661x; 1.2661x over previous
//
#include <hip/hip_runtime.h>
#include <hip/hip_bf16.h>

#define D 64

typedef unsigned short u16;
typedef unsigned long long u64;
typedef __attribute__((ext_vector_type(8))) unsigned short u16x8;

static __device__ __forceinline__ u16 f2bf(float f) {
    unsigned u = __float_as_uint(f);
    unsigned r = (u + 0x7FFFu + ((u >> 16) & 1u)) >> 16;   // RNE
    return (u16)r;
}
static __device__ __forceinline__ float bf2f(u16 h) {
    return __uint_as_float(((unsigned)h) << 16);
}

// ---------------------------------------------------------------------------
__global__ void out_init_kernel(float* __restrict__ out, const float* __restrict__ bout, int G) {
    int i = blockIdx.x * blockDim.x + threadIdx.x;
    if (i < G) out[i] = bout[0];
}

// ---------------------------------------------------------------------------
// CSR build: histogram -> scan
// ---------------------------------------------------------------------------
__global__ void deg_hist_kernel(const int* __restrict__ ei, int* __restrict__ deg, int E) {
    int e = blockIdx.x * blockDim.x + threadIdx.x;
    if (e < E) atomicAdd(&deg[ei[E + e]], 1);
}

__global__ __launch_bounds__(1024) void scan1_kernel(
    const int* __restrict__ deg, int* __restrict__ off, int* __restrict__ bsum, int N)
{
    __shared__ int sh[1024];
    int t = threadIdx.x;
    int i = blockIdx.x * 1024 + t;
    int v = (i < N) ? deg[i] : 0;
    sh[t] = v;
    __syncthreads();
#pragma unroll
    for (int o = 1; o < 1024; o <<= 1) {
        int u = (t >= o) ? sh[t - o] : 0;
        __syncthreads();
        sh[t] += u;
        __syncthreads();
    }
    if (i < N) off[i] = sh[t] - v;
    if (t == 1023) bsum[blockIdx.x] = sh[t];
}

__global__ __launch_bounds__(128) void scan2_kernel(
    const int* __restrict__ bsum, int* __restrict__ boff, int nb)
{
    __shared__ int sh[128];
    int t = threadIdx.x;
    int v = (t < nb) ? bsum[t] : 0;
    sh[t] = v;
    __syncthreads();
#pragma unroll
    for (int o = 1; o < 128; o <<= 1) {
        int u = (t >= o) ? sh[t - o] : 0;
        __syncthreads();
        sh[t] += u;
        __syncthreads();
    }
    if (t < nb) boff[t] = sh[t] - v;
}

__global__ void scan3_kernel(int* __restrict__ off, const int* __restrict__ boff, int N) {
    int i = blockIdx.x * blockDim.x + threadIdx.x;
    if (i < N) off[i] += boff[i >> 10];
}

// ---------------------------------------------------------------------------
// build: fused scatter + reorder.  Wave handles 4 edges, 16 lanes/edge.
// Sequential fp32 ea read, bf16 row (128B) write to CSR slot.
// Non-temporal 8B stores keep the scattered write stream out of L2.
// ---------------------------------------------------------------------------
__global__ __launch_bounds__(256) void build_kernel(
    const float* __restrict__ ea, const int* __restrict__ ei,
    const int* __restrict__ off, int* __restrict__ cur,
    int* __restrict__ src_csr, u16* __restrict__ ea_csr, int E)
{
    const int lane = threadIdx.x & 63;
    const int q = lane & 15, g = lane >> 4;
    const long long wv = (long long)blockIdx.x * 4 + (threadIdx.x >> 6);
    const int e = (int)(wv * 4) + g;

    int p = 0, s = 0;
    if (e < E && q == 0) {
        int d = ei[E + e];
        s = ei[e];
        p = off[d] + atomicAdd(&cur[d], 1);
    }
    p = __shfl(p, lane & 48, 64);        // broadcast group leader's slot
    if (e >= E) return;

    float4 v = *(const float4*)&ea[(size_t)e * D + q * 4];
    u64 pk = (u64)f2bf(v.x) | ((u64)f2bf(v.y) << 16)
           | ((u64)f2bf(v.z) << 32) | ((u64)f2bf(v.w) << 48);
    __builtin_nontemporal_store(pk, (u64*)&ea_csr[(size_t)p * D + q * 4]);
    if (q == 0) src_csr[p] = s;
}

// ---------------------------------------------------------------------------
// convx: fp32 node features -> bf16 (identity order, fully sequential)
// ---------------------------------------------------------------------------
__global__ __launch_bounds__(256) void convx_kernel(
    const float* __restrict__ xf, u16* __restrict__ xb, long long n4)
{
    long long i = (long long)blockIdx.x * blockDim.x + threadIdx.x;
    if (i >= n4) return;
    float4 v = ((const float4*)xf)[i];
    ushort4 o;
    o.x = f2bf(v.x); o.y = f2bf(v.y); o.z = f2bf(v.z); o.w = f2bf(v.w);
    ((ushort4*)xb)[i] = o;
}

// ---------------------------------------------------------------------------
// aggregate v2: wave per node, 8 lanes/edge, 8 edges per chunk.
//  - all src indices preloaded in ONE coalesced load (deg<=64), shfl-spread
//  - 2-deep chunk pipeline: chunk c+1's loads issue before chunk c consumes
//  - partial chunk via clamp+mask (all load streams stay full, branchless)
// ---------------------------------------------------------------------------
__global__ __launch_bounds__(256) void aggregate_kernel(
    const u16* __restrict__ xbf, const u16* __restrict__ ea_csr,
    const int* __restrict__ src_csr, const int* __restrict__ off,
    const int* __restrict__ deg, float* __restrict__ h, int N)
{
    const int lane = threadIdx.x & 63;
    const int sub  = lane & 7;        // dim octet
    const int g    = lane >> 3;       // edge slot 0..7
    const int n = (blockIdx.x << 2) + (threadIdx.x >> 6);
    if (n >= N) return;

    const int p0 = off[n];
    const int dg = deg[n];

    u16x8 xs;                          // self row (consumed at the end)
    if (g == 0) xs = *(const u16x8*)&xbf[(size_t)n * D + sub * 8];

    float a0=0.f,a1=0.f,a2=0.f,a3=0.f,a4=0.f,a5=0.f,a6=0.f,a7=0.f;

    if (dg > 0) {
        const int srcAll = src_csr[p0 + min(lane, dg - 1)];  // one coalesced load
        const int nct = (dg + 7) >> 3;

        // ---- issue chunk 0 ----
        int e0 = min(g, dg - 1);
        int sv = __shfl(srcAll, e0 & 63, 64);
        int s0 = (e0 < 64) ? sv : src_csr[p0 + e0];
        u16x8 evA = *(const u16x8*)&ea_csr[(size_t)(p0 + e0) * D + sub * 8];
        u16x8 xvA = *(const u16x8*)&xbf[(size_t)s0 * D + sub * 8];
        float mA = (g < dg) ? 1.f : 0.f;

        for (int c = 1; c < nct; ++c) {
            // ---- issue chunk c while consuming chunk c-1 ----
            int e1 = min(c * 8 + g, dg - 1);
            int sv1 = __shfl(srcAll, e1 & 63, 64);
            int s1 = (e1 < 64) ? sv1 : src_csr[p0 + e1];
            u16x8 evB = *(const u16x8*)&ea_csr[(size_t)(p0 + e1) * D + sub * 8];
            u16x8 xvB = *(const u16x8*)&xbf[(size_t)s1 * D + sub * 8];
            float mB = (c * 8 + g < dg) ? 1.f : 0.f;

            a0 = fmaf(mA, fmaxf(bf2f(xvA[0]) + bf2f(evA[0]), 0.f), a0);
            a1 = fmaf(mA, fmaxf(bf2f(xvA[1]) + bf2f(evA[1]), 0.f), a1);
            a2 = fmaf(mA, fmaxf(bf2f(xvA[2]) + bf2f(evA[2]), 0.f), a2);
            a3 = fmaf(mA, fmaxf(bf2f(xvA[3]) + bf2f(evA[3]), 0.f), a3);
            a4 = fmaf(mA, fmaxf(bf2f(xvA[4]) + bf2f(evA[4]), 0.f), a4);
            a5 = fmaf(mA, fmaxf(bf2f(xvA[5]) + bf2f(evA[5]), 0.f), a5);
            a6 = fmaf(mA, fmaxf(bf2f(xvA[6]) + bf2f(evA[6]), 0.f), a6);
            a7 = fmaf(mA, fmaxf(bf2f(xvA[7]) + bf2f(evA[7]), 0.f), a7);

            evA = evB; xvA = xvB; mA = mB;
        }
        // ---- consume last chunk ----
        a0 = fmaf(mA, fmaxf(bf2f(xvA[0]) + bf2f(evA[0]), 0.f), a0);
        a1 = fmaf(mA, fmaxf(bf2f(xvA[1]) + bf2f(evA[1]), 0.f), a1);
        a2 = fmaf(mA, fmaxf(bf2f(xvA[2]) + bf2f(evA[2]), 0.f), a2);
        a3 = fmaf(mA, fmaxf(bf2f(xvA[3]) + bf2f(evA[3]), 0.f), a3);
        a4 = fmaf(mA, fmaxf(bf2f(xvA[4]) + bf2f(evA[4]), 0.f), a4);
        a5 = fmaf(mA, fmaxf(bf2f(xvA[5]) + bf2f(evA[5]), 0.f), a5);
        a6 = fmaf(mA, fmaxf(bf2f(xvA[6]) + bf2f(evA[6]), 0.f), a6);
        a7 = fmaf(mA, fmaxf(bf2f(xvA[7]) + bf2f(evA[7]), 0.f), a7);
    }

    // reduce across the 8 edge-groups (dims live in sub, same for all g)
#pragma unroll
    for (int o = 8; o < 64; o <<= 1) {
        a0 += __shfl_xor(a0, o, 64);  a1 += __shfl_xor(a1, o, 64);
        a2 += __shfl_xor(a2, o, 64);  a3 += __shfl_xor(a3, o, 64);
        a4 += __shfl_xor(a4, o, 64);  a5 += __shfl_xor(a5, o, 64);
        a6 += __shfl_xor(a6, o, 64);  a7 += __shfl_xor(a7, o, 64);
    }

    if (g == 0) {
        float4 lo, hi;
        lo.x = a0 + bf2f(xs[0]); lo.y = a1 + bf2f(xs[1]);
        lo.z = a2 + bf2f(xs[2]); lo.w = a3 + bf2f(xs[3]);
        hi.x = a4 + bf2f(xs[4]); hi.y = a5 + bf2f(xs[5]);
        hi.z = a6 + bf2f(xs[6]); hi.w = a7 + bf2f(xs[7]);
        *(float4*)&h[(size_t)n * D + sub * 8]     = lo;
        *(float4*)&h[(size_t)n * D + sub * 8 + 4] = hi;
    }
}

// ---------------------------------------------------------------------------
// MLP: relu(relu(h@W1+b1)@W2+b2). Weights pinned in VGPRs ((256,1) -> cap 512,
// pin holds); wave-local LDS broadcast; 4 partial accumulators. Writes bf16 x.
// LAST=1 fuses pool + Wout.
// ---------------------------------------------------------------------------
template <int LAST>
__global__ __launch_bounds__(256, 1) void mlp_kernel(
    const float* __restrict__ hin, u16* __restrict__ xout,
    const float* __restrict__ W1, const float* __restrict__ b1,
    const float* __restrict__ W2, const float* __restrict__ b2,
    const int* __restrict__ batch, const float* __restrict__ Wout,
    float* __restrict__ out, int N, int chunk)
{
    __shared__ __align__(16) float sh[4][D];
    __shared__ __align__(16) float sh2[4][D];

    const int lane = threadIdx.x & 63;
    const int wid  = threadIdx.x >> 6;

    float w1[D], w2[D];
#pragma unroll
    for (int k = 0; k < D; ++k) w1[k] = W1[k * D + lane];
#pragma unroll
    for (int k = 0; k < D; ++k) w2[k] = W2[k * D + lane];
#pragma unroll
    for (int k = 0; k < D; ++k) { asm volatile("" : "+v"(w1[k])); asm volatile("" : "+v"(w2[k])); }
    const float b1l = b1[lane];
    const float b2l = b2[lane];
    const float wo  = LAST ? Wout[lane] : 0.f;

    const int w = (blockIdx.x << 2) + wid;
    int n0 = w * chunk;
    if (n0 >= N) return;
    int n1 = min(n0 + chunk, N);

    float gsum = 0.f;
    int   curg = -1;

    for (int n = n0; n < n1; ++n) {
        float hv = hin[(size_t)n * D + lane];
        sh[wid][lane] = hv;

        float t0 = 0.f, t1 = 0.f, t2 = 0.f, t3 = 0.f;
#pragma unroll
        for (int k = 0; k < D; k += 4) {
            float4 hk = *(const float4*)&sh[wid][k];
            t0 = fmaf(hk.x, w1[k + 0], t0);
            t1 = fmaf(hk.y, w1[k + 1], t1);
            t2 = fmaf(hk.z, w1[k + 2], t2);
            t3 = fmaf(hk.w, w1[k + 3], t3);
        }
        float hid = fmaxf(((t0 + t1) + (t2 + t3)) + b1l, 0.f);
        sh2[wid][lane] = hid;

        float s0 = 0.f, s1 = 0.f, s2 = 0.f, s3 = 0.f;
#pragma unroll
        for (int k = 0; k < D; k += 4) {
            float4 hk = *(const float4*)&sh2[wid][k];
            s0 = fmaf(hk.x, w2[k + 0], s0);
            s1 = fmaf(hk.y, w2[k + 1], s1);
            s2 = fmaf(hk.z, w2[k + 2], s2);
            s3 = fmaf(hk.w, w2[k + 3], s3);
        }
        float r = fmaxf(((s0 + s1) + (s2 + s3)) + b2l, 0.f);

        if (LAST) {
            float s = r * wo;
#pragma unroll
            for (int o = 32; o; o >>= 1) s += __shfl_xor(s, o, 64);
            int gb = batch[n];
            if (gb != curg) {
                if (curg >= 0 && lane == 0) atomicAdd(&out[curg], gsum);
                curg = gb;
                gsum = s;
            } else {
                gsum += s;
            }
        } else {
            xout[(size_t)n * D + lane] = f2bf(r);
        }
    }
    if (LAST && curg >= 0 && lane == 0) atomicAdd(&out[curg], gsum);
}

// ---------------------------------------------------------------------------
extern "C" void kernel_launch(void* const* d_in, const int* in_sizes, int n_in,
                              void* d_out, int out_size, void* d_ws, size_t ws_size,
                              hipStream_t stream) {
    const float* x     = (const float*)d_in[0];
    const int*   ei    = (const int*)d_in[1];
    const float* ea    = (const float*)d_in[2];
    const int*   batch = (const int*)d_in[3];
    const float* W1    = (const float*)d_in[4];
    const float* b1    = (const float*)d_in[5];
    const float* W2    = (const float*)d_in[6];
    const float* b2    = (const float*)d_in[7];
    const float* Wout  = (const float*)d_in[8];
    const float* bout  = (const float*)d_in[9];
    float* out = (float*)d_out;

    const int N = in_sizes[0] / D;   // 100000
    const int E = in_sizes[1] / 2;   // 1200000
    const int G = out_size;          // 128

    // ---- workspace layout ----
    char* w = (char*)d_ws;
    u16*   xbfA    = (u16*)w;              w += (size_t)N * D * sizeof(u16);
    u16*   xbfB    = (u16*)w;              w += (size_t)N * D * sizeof(u16);
    float* hbuf    = (float*)w;            w += (size_t)N * D * sizeof(float);
    int*   src_csr = (int*)w;              w += (size_t)E * sizeof(int);
    int*   deg     = (int*)w;              w += (size_t)N * sizeof(int);
    int*   off     = (int*)w;              w += (size_t)N * sizeof(int);
    int*   cur     = (int*)w;              w += (size_t)N * sizeof(int);
    int*   bsum    = (int*)w;              w += 128 * sizeof(int);
    int*   boff    = (int*)w;              w += 128 * sizeof(int);
    u16*   ea_csr  = (u16*)w;              // E*D*2 bytes

    const int nScanBlocks = (N + 1023) / 1024;
    const int edgeBlocks  = (E + 255) / 256;
    const int buildBlocks = (E + 15) / 16;
    const int aggBlocks   = (N + 3) / 4;       // one wave per node

    const long long nx4 = (long long)N * D / 4;
    const int convxBlocks = (int)((nx4 + 255) / 256);

    const int mlpWaves  = 4096;
    const int mlpBlocks = mlpWaves / 4;
    const int chunk     = (N + mlpWaves - 1) / mlpWaves;

    out_init_kernel<<<(G + 127) / 128, 128, 0, stream>>>(out, bout, G);

    // ---- CSR build + bf16 edge reorder + x0 bf16 convert ----
    hipMemsetAsync(deg, 0, (size_t)N * sizeof(int), stream);
    hipMemsetAsync(cur, 0, (size_t)N * sizeof(int), stream);
    deg_hist_kernel<<<edgeBlocks, 256, 0, stream>>>(ei, deg, E);
    scan1_kernel<<<nScanBlocks, 1024, 0, stream>>>(deg, off, bsum, N);
    scan2_kernel<<<1, 128, 0, stream>>>(bsum, boff, nScanBlocks);
    scan3_kernel<<<(N + 255) / 256, 256, 0, stream>>>(off, boff, N);
    build_kernel<<<buildBlocks, 256, 0, stream>>>(ea, ei, off, cur, src_csr, ea_csr, E);
    convx_kernel<<<convxBlocks, 256, 0, stream>>>(x, xbfA, nx4);

    // ---- 3 layers: aggregate -> mlp ----
    u16* xcur = xbfA;
    u16* xnxt = xbfB;
    for (int l = 0; l < 3; ++l) {
        aggregate_kernel<<<aggBlocks, 256, 0, stream>>>(xcur, ea_csr, src_csr,
                                                        off, deg, hbuf, N);
        if (l < 2) {
            mlp_kernel<0><<<mlpBlocks, 256, 0, stream>>>(hbuf, xnxt,
                W1 + l * D * D, b1 + l * D, W2 + l * D * D, b2 + l * D,
                batch, Wout, out, N, chunk);
            u16* t = xcur; xcur = xnxt; xnxt = t;
        } else {
            mlp_kernel<1><<<mlpBlocks, 256, 0, stream>>>(hbuf, nullptr,
                W1 + l * D * D, b1 + l * D, W2 + l * D * D, b2 + l * D,
                batch, Wout, out, N, chunk);
        }
    }
}